// Round 9
// baseline (513.328 us; speedup 1.0000x reference)
//
#include <hip/hip_runtime.h>
#include <hip/hip_bf16.h>
#include <math.h>

// SNN 3-layer LIF MLP, T=10, fp32 reference.
// R9: = R8 with gemm_i8 K-loop unrolled to BK=128 (two 64-K MFMA steps per
// barrier pair). LDS 40 KB/block -> still 3 blocks/CU (m132's BK=128 regression
// was the 64 KB occupancy cliff; i8 tiles are half-size so we keep occupancy).
// Halves barrier count; doubles MFMA work per vmcnt drain.
// Numerics byte-identical to R8 (i8 digit planes, exact i64 combine).

typedef _Float16 half8 __attribute__((ext_vector_type(8)));
typedef __attribute__((ext_vector_type(4))) float f32x4;
typedef __attribute__((ext_vector_type(4))) int i32x4;

#ifndef __has_builtin
#define __has_builtin(x) 0
#endif
#if __has_builtin(__builtin_amdgcn_global_load_lds)
#define HAS_GLLDS 1
#else
#define HAS_GLLDS 0
#endif

// slot swizzle for (row r in [0,64), chunk c in [0,4)) -> granule slot
__device__ __forceinline__ int swz(int r, int c) {
    const int s2 = r >> 1;
    return s2 * 8 + ((((r & 1) << 2) + c + s2) & 7);
}

// ------------------------------------------------------------- i8 digit GEMM
// C[M][Npad] = (2^16*S@W2d + 2^8*S@W1d + S@W0d) * 2^-s ; S i8 binary.
// Block tile 128m x 64n, wave tile 64x32, BK=128 (2 k-steps per barrier).
__global__ __launch_bounds__(256, 3)
void gemm_i8(const signed char* __restrict__ A, int lda,
             const signed char* __restrict__ Bd, size_t bStride, int ldb,
             int K, const unsigned* __restrict__ maxbits,
             float* __restrict__ C, int Npad, int ls)
{
    // 10 sub-tiles of 4KB: [h=0: A0 A1 B0 B1 B2][h=1: A0 A1 B0 B1 B2]
    __shared__ __align__(16) char tiles[10 * 4096];

    const int tid = threadIdx.x;
    const int b   = blockIdx.x;
    const int xcd = b & 7, ii = b >> 3;
    const int ntp = 1 << ls;
    const int n_tile = xcd * ntp + (ii & (ntp - 1));
    const int m_tile = ii >> ls;
    const int m0 = m_tile * 128, n0 = n_tile * 64;

    const int ss = tid >> 3;
    const int gg = ((tid & 7) - ss) & 7;
    const int rdec = 2 * ss + (gg >> 2);   // 0..63
    const int cdec = gg & 3;
    const int wbase = (tid & ~63) * 16;    // wave-uniform LDS dest base

    const signed char* srcA0 = A + (size_t)(m0 + rdec) * lda + cdec * 16;
    const signed char* srcA1 = A + (size_t)(m0 + 64 + rdec) * lda + cdec * 16;
    const signed char* srcB[3];
    #pragma unroll
    for (int q = 0; q < 3; ++q)
        srcB[q] = Bd + q * bStride + (size_t)(n0 + rdec) * ldb + cdec * 16;

    const int lane = tid & 63, w = tid >> 6;
    const int wm = (w >> 1) * 64, wn = (w & 1) * 32;
    const int lm = lane & 15, ck = lane >> 4;

    int aOff[4], bOff[2];
    #pragma unroll
    for (int i = 0; i < 4; ++i) {
        const int r = wm + i * 16 + lm;
        aOff[i] = (r >> 6) * 4096 + swz(r & 63, ck) * 16;
    }
    #pragma unroll
    for (int j = 0; j < 2; ++j) {
        const int r = wn + j * 16 + lm;
        bOff[j] = 8192 + swz(r, ck) * 16;
    }

    i32x4 acc0[4][2] = {}, acc1[4][2] = {}, acc2[4][2] = {};

    const int nIter = K / 128;
    for (int it = 0; it < nIter; ++it) {
        const int kk = it * 128;
        #pragma unroll
        for (int h = 0; h < 2; ++h) {
            const int kh = kk + h * 64;
            char* tb = tiles + h * 20480;
#if HAS_GLLDS
            __builtin_amdgcn_global_load_lds(
                (const __attribute__((address_space(1))) void*)(srcA0 + kh),
                (__attribute__((address_space(3))) void*)(tb + wbase), 16, 0, 0);
            __builtin_amdgcn_global_load_lds(
                (const __attribute__((address_space(1))) void*)(srcA1 + kh),
                (__attribute__((address_space(3))) void*)(tb + 4096 + wbase), 16, 0, 0);
            #pragma unroll
            for (int q = 0; q < 3; ++q)
                __builtin_amdgcn_global_load_lds(
                    (const __attribute__((address_space(1))) void*)(srcB[q] + kh),
                    (__attribute__((address_space(3))) void*)(tb + 8192 + q * 4096 + wbase),
                    16, 0, 0);
#else
            *(float4*)(tb + tid * 16) = *(const float4*)(srcA0 + kh);
            *(float4*)(tb + 4096 + tid * 16) = *(const float4*)(srcA1 + kh);
            #pragma unroll
            for (int q = 0; q < 3; ++q)
                *(float4*)(tb + 8192 + q * 4096 + tid * 16) = *(const float4*)(srcB[q] + kh);
#endif
        }
        __syncthreads();

        #pragma unroll
        for (int h = 0; h < 2; ++h) {
            const char* tb = tiles + h * 20480;
            i32x4 aF[4], bF[3][2];
            #pragma unroll
            for (int i = 0; i < 4; ++i) aF[i] = *(const i32x4*)(tb + aOff[i]);
            #pragma unroll
            for (int q = 0; q < 3; ++q)
                #pragma unroll
                for (int j = 0; j < 2; ++j)
                    bF[q][j] = *(const i32x4*)(tb + q * 4096 + bOff[j]);

            #pragma unroll
            for (int i = 0; i < 4; ++i)
                #pragma unroll
                for (int j = 0; j < 2; ++j) {
                    acc0[i][j] = __builtin_amdgcn_mfma_i32_16x16x64_i8(aF[i], bF[0][j], acc0[i][j], 0, 0, 0);
                    acc1[i][j] = __builtin_amdgcn_mfma_i32_16x16x64_i8(aF[i], bF[1][j], acc1[i][j], 0, 0, 0);
                    acc2[i][j] = __builtin_amdgcn_mfma_i32_16x16x64_i8(aF[i], bF[2][j], acc2[i][j], 0, 0, 0);
                }
        }
        __syncthreads();
    }

    // epilogue: exact i64 digit combine, one fp32 round * 2^-s
    const int sexp = 21 - ilogbf(__uint_as_float(*maxbits));
    const float sc = ldexpf(1.0f, -sexp);
    const int rq = ck * 4;
    #pragma unroll
    for (int i = 0; i < 4; ++i) {
        #pragma unroll
        for (int j = 0; j < 2; ++j) {
            const int n = n0 + wn + j * 16 + lm;
            #pragma unroll
            for (int r = 0; r < 4; ++r) {
                const int m = m0 + wm + i * 16 + rq + r;
                const long long v = ((long long)acc0[i][j][r] << 16) +
                                    ((long long)acc1[i][j][r] << 8) +
                                    (long long)acc2[i][j][r];
                C[(size_t)m * Npad + n] = (float)v * sc;
            }
        }
    }
}

// --------------------------------------------------------- L1 f16 2-plane GEMM
// 2 A-planes x 2 B-planes, pairs (0,0)(0,1)(1,0). Block 128x128, wave 64x64.
__global__ __launch_bounds__(256)
void gemm_f16_l1(const _Float16* __restrict__ A, size_t aStride, int lda,
                 const _Float16* __restrict__ B, size_t bStride, int ldb,
                 int K, int kChunk, float scale,
                 float* __restrict__ C, int Npad, int ls)
{
    __shared__ __align__(16) char tiles[4 * 8192];

    const int tid = threadIdx.x;
    const int b   = blockIdx.x;
    const int xcd = b & 7, ii = b >> 3;
    const int ntp = 1 << ls;
    const int n_tile = xcd * ntp + (ii & (ntp - 1));
    const int m_tile = ii >> ls;
    const int m0 = m_tile * 128, n0 = n_tile * 128;

    const int t     = m0 >> 10;
    const int kbase = t * kChunk;
    const int arow0 = m0 & 1023;

    int srow[2], schk[2];
    #pragma unroll
    for (int h = 0; h < 2; ++h) {
        const int s   = h * 256 + tid;
        const int sub = s >> 8, sp = s & 255;
        const int ss  = sp >> 3, gg = ((sp & 7) - ss) & 7;
        srow[h] = sub * 64 + 2 * ss + (gg >> 2);
        schk[h] = gg & 3;
    }
    const int wbase = (tid & ~63) * 16;

    const _Float16* srcA[2][2];
    const _Float16* srcB[2][2];
    #pragma unroll
    for (int p = 0; p < 2; ++p)
        #pragma unroll
        for (int h = 0; h < 2; ++h) {
            srcA[p][h] = A + p * aStride + (size_t)(arow0 + srow[h]) * lda + kbase + schk[h] * 8;
            srcB[p][h] = B + p * bStride + (size_t)(n0 + srow[h]) * ldb + kbase + schk[h] * 8;
        }

    const int lane = tid & 63, w = tid >> 6;
    const int wm = (w >> 1) * 64, wn = (w & 1) * 64;
    const int lm = lane & 15, ck = lane >> 4;

    int aOff[4], bOff[4];
    #pragma unroll
    for (int i = 0; i < 4; ++i) {
        const int r = wm + i * 16 + lm;
        aOff[i] = (r >> 6) * 4096 + swz(r & 63, ck) * 16;
        const int r2 = wn + i * 16 + lm;
        bOff[i] = (r2 >> 6) * 4096 + swz(r2 & 63, ck) * 16;
    }

    f32x4 acc[4][4] = {};

    const int nIter = K / 32;
    for (int it = 0; it < nIter; ++it) {
        const int kk = it * 32;
        #pragma unroll
        for (int p = 0; p < 2; ++p)
            #pragma unroll
            for (int h = 0; h < 2; ++h) {
#if HAS_GLLDS
                __builtin_amdgcn_global_load_lds(
                    (const __attribute__((address_space(1))) void*)(srcA[p][h] + kk),
                    (__attribute__((address_space(3))) void*)(tiles + p * 8192 + h * 4096 + wbase),
                    16, 0, 0);
                __builtin_amdgcn_global_load_lds(
                    (const __attribute__((address_space(1))) void*)(srcB[p][h] + kk),
                    (__attribute__((address_space(3))) void*)(tiles + (2 + p) * 8192 + h * 4096 + wbase),
                    16, 0, 0);
#else
                *(float4*)(tiles + p * 8192 + (h * 256 + tid) * 16) = *(const float4*)(srcA[p][h] + kk);
                *(float4*)(tiles + (2 + p) * 8192 + (h * 256 + tid) * 16) = *(const float4*)(srcB[p][h] + kk);
#endif
            }
        __syncthreads();

        half8 aF[2][4], bF[2][4];
        #pragma unroll
        for (int p = 0; p < 2; ++p)
            #pragma unroll
            for (int i = 0; i < 4; ++i) {
                aF[p][i] = *(const half8*)(tiles + p * 8192 + aOff[i]);
                bF[p][i] = *(const half8*)(tiles + (2 + p) * 8192 + bOff[i]);
            }

        constexpr int PA[3] = {0,0,1}, PB[3] = {0,1,0};
        #pragma unroll
        for (int pp = 0; pp < 3; ++pp)
            #pragma unroll
            for (int i = 0; i < 4; ++i)
                #pragma unroll
                for (int j = 0; j < 4; ++j)
                    acc[i][j] = __builtin_amdgcn_mfma_f32_16x16x32_f16(
                        aF[PA[pp]][i], bF[PB[pp]][j], acc[i][j], 0, 0, 0);
        __syncthreads();
    }

    const int rq = ck * 4;
    #pragma unroll
    for (int i = 0; i < 4; ++i)
        #pragma unroll
        for (int j = 0; j < 4; ++j) {
            const int n = n0 + wn + j * 16 + lm;
            #pragma unroll
            for (int r = 0; r < 4; ++r) {
                const int m = m0 + wm + i * 16 + rq + r;
                C[(size_t)m * Npad + n] = acc[i][j][r] * scale;
            }
        }
}

// ------------------------------------------------------------------ LIF scan
__global__ __launch_bounds__(256)
void lif_scan(const float* __restrict__ C, const float* __restrict__ bias,
              signed char* __restrict__ sout,      // i8 spikes, nullable
              float* __restrict__ fout,            // nullable: t=9, n<Nreal
              int Hpad, int Nreal, int prefix)
{
    const int W4 = Hpad >> 2;
    const int idx = blockIdx.x * 256 + threadIdx.x;
    if (idx >= (W4 << 10)) return;
    const int bb = idx / W4, n4 = idx - bb * W4;
    const float4 b4 = *(const float4*)(bias + n4 * 4);
    const float bs[4] = {b4.x, b4.y, b4.z, b4.w};
    float v[4] = {0.f,0.f,0.f,0.f}, c[4] = {0.f,0.f,0.f,0.f};
    for (int t = 0; t < 10; ++t) {
        const size_t row = (size_t)((t << 10) + bb);
        const float4 p4 = *(const float4*)(C + row * Hpad + n4 * 4);
        const float pv[4] = {p4.x, p4.y, p4.z, p4.w};
        float sv[4];
        #pragma unroll
        for (int e = 0; e < 4; ++e) {
            c[e] = prefix ? (c[e] + pv[e]) : pv[e];
            const float vv = (v[e] + (c[e] + bs[e])) * 0.5f;
            const float sp = (vv >= 1.0f) ? 1.0f : 0.0f;
            v[e] = (sp != 0.0f) ? 0.0f : vv;
            sv[e] = sp;
        }
        if (sout) {
            unsigned pack = 0;
            #pragma unroll
            for (int e = 0; e < 4; ++e) pack |= (sv[e] != 0.0f ? 1u : 0u) << (8 * e);
            *(unsigned*)(sout + row * Hpad + n4 * 4) = pack;
        }
        if (fout && t == 9) {
            #pragma unroll
            for (int e = 0; e < 4; ++e) {
                const int n = n4 * 4 + e;
                if (n < Nreal) fout[(size_t)bb * Nreal + n] = sv[e];
            }
        }
    }
}

// --------------------------------------------- fused maxabs (W2 and W3 in one)
__global__ __launch_bounds__(256)
void maxabs2_kern(const float* __restrict__ w2, int n2,
                  const float* __restrict__ w3, int n3,
                  unsigned* __restrict__ out)
{
    const float* w = blockIdx.y ? w3 : w2;
    const int n = blockIdx.y ? n3 : n2;
    float m = 0.f;
    for (int i = blockIdx.x * 256 + threadIdx.x; i < n; i += gridDim.x * 256)
        m = fmaxf(m, fabsf(w[i]));
    #pragma unroll
    for (int off = 32; off > 0; off >>= 1)
        m = fmaxf(m, __shfl_down(m, off, 64));
    if ((threadIdx.x & 63) == 0) atomicMax(out + blockIdx.y, __float_as_uint(m));
}

// ----------------------------------------------- W digit split (3 i8 planes)
__global__ __launch_bounds__(256)
void dsplit_t(const float* __restrict__ W, int K, int Nreal, int Npad,
              signed char* __restrict__ out, const unsigned* __restrict__ maxbits)
{
    __shared__ float tl[32][33];
    const int sexp = 21 - ilogbf(__uint_as_float(*maxbits));
    const float fs = ldexpf(1.0f, sexp);
    const int k0 = blockIdx.x * 32, n0 = blockIdx.y * 32;
    const int tx = threadIdx.x & 31, ty = threadIdx.x >> 5;
    #pragma unroll
    for (int i = 0; i < 4; ++i) {
        const int k = k0 + ty + i * 8, n = n0 + tx;
        tl[ty + i * 8][tx] = (n < Nreal) ? W[(size_t)k * Nreal + n] : 0.f;
    }
    __syncthreads();
    const size_t plane = (size_t)Npad * K;
    #pragma unroll
    for (int i = 0; i < 4; ++i) {
        const int n = n0 + ty + i * 8, k = k0 + tx;
        int wi = (int)lrintf(tl[tx][ty + i * 8] * fs);
        const int d0 = ((wi + 128) & 255) - 128; wi = (wi - d0) >> 8;
        const int d1 = ((wi + 128) & 255) - 128; wi = (wi - d1) >> 8;
        const size_t idx = (size_t)n * K + k;
        out[idx]             = (signed char)wi;   // high digit (2^16)
        out[plane + idx]     = (signed char)d1;   // mid  digit (2^8)
        out[2 * plane + idx] = (signed char)d0;   // low  digit (2^0)
    }
}

// ------------------------------------------------- L1 f16 splits (2^8-scaled)
__device__ __forceinline__ void f16split2(float val, _Float16& hi, _Float16& mid) {
    const float vs = val * 256.0f;
    hi = (_Float16)vs;
    mid = (_Float16)(vs - (float)hi);
}

__global__ __launch_bounds__(256)
void split2_w1(const float* __restrict__ W1, _Float16* __restrict__ out)
{
    __shared__ float tl[32][33];
    const int kk0 = blockIdx.x * 32, n0 = blockIdx.y * 32;
    const int tx = threadIdx.x & 31, ty = threadIdx.x >> 5;
    #pragma unroll
    for (int i = 0; i < 4; ++i) {
        const int kk = kk0 + ty + i * 8;
        const int tt = kk / 416, j = kk - tt * 416;
        tl[ty + i * 8][tx] = (j < 400) ? W1[(size_t)(tt * 400 + j) * 2048 + (n0 + tx)] : 0.f;
    }
    __syncthreads();
    const size_t plane = (size_t)2048 * 4160;
    #pragma unroll
    for (int i = 0; i < 4; ++i) {
        const int n = n0 + ty + i * 8, kk = kk0 + tx;
        _Float16 hi, mid;
        f16split2(tl[tx][ty + i * 8], hi, mid);
        const size_t idx = (size_t)n * 4160 + kk;
        out[idx] = hi; out[plane + idx] = mid;
    }
}

__global__ __launch_bounds__(256)
void splitx(const float* __restrict__ x, _Float16* __restrict__ out)
{
    const int id = blockIdx.x * 256 + threadIdx.x;
    if (id >= 1024 * 4160) return;
    const int m = id / 4160, kk = id - m * 4160;
    const int tt = kk / 416, j = kk - tt * 416;
    const float val = (j < 400) ? x[(size_t)m * 4000 + tt * 400 + j] : 0.f;
    const size_t PS = (size_t)1024 * 4160;
    _Float16 hi, mid;
    f16split2(val, hi, mid);
    out[id] = hi; out[PS + id] = mid;
}

// -------------------------------------- fallback fp32 path (small workspace)
__global__ __launch_bounds__(256)
void gemm_lif_f32fb(const float* __restrict__ A, int lda,
                    const float* __restrict__ B, int ldb,
                    const float* __restrict__ bias,
                    float* __restrict__ cacc, float* __restrict__ v,
                    float* __restrict__ s, int M, int N, int K)
{
    __shared__ float As[16][68];
    __shared__ float Bs[16][68];
    const int tid = threadIdx.x;
    const int tx = tid & 15, ty = tid >> 4;
    const int row0 = blockIdx.y * 64, col0 = blockIdx.x * 64;
    const int am = tid >> 2, ak = (tid & 3) * 4;
    const int bk = tid >> 4, bn = (tid & 15) * 4;
    float acc[4][4];
    #pragma unroll
    for (int i = 0; i < 4; ++i)
        #pragma unroll
        for (int j = 0; j < 4; ++j) acc[i][j] = 0.f;
    for (int k0 = 0; k0 < K; k0 += 16) {
        const float4 a4 = *(const float4*)(A + (size_t)(row0 + am) * lda + (k0 + ak));
        As[ak + 0][am] = a4.x; As[ak + 1][am] = a4.y;
        As[ak + 2][am] = a4.z; As[ak + 3][am] = a4.w;
        {
            const int col = col0 + bn;
            const float* bp = B + (size_t)(k0 + bk) * ldb + col;
            float4 b4;
            if (col + 3 < N) b4 = *(const float4*)bp;
            else {
                b4.x = (col + 0 < N) ? bp[0] : 0.f;
                b4.y = (col + 1 < N) ? bp[1] : 0.f;
                b4.z = (col + 2 < N) ? bp[2] : 0.f;
                b4.w = 0.f;
            }
            *(float4*)&Bs[bk][bn] = b4;
        }
        __syncthreads();
        #pragma unroll
        for (int kk = 0; kk < 16; ++kk) {
            float af[4], bf[4];
            #pragma unroll
            for (int i = 0; i < 4; ++i) af[i] = As[kk][ty * 4 + i];
            #pragma unroll
            for (int j = 0; j < 4; ++j) bf[j] = Bs[kk][tx * 4 + j];
            #pragma unroll
            for (int i = 0; i < 4; ++i)
                #pragma unroll
                for (int j = 0; j < 4; ++j) acc[i][j] += af[i] * bf[j];
        }
        __syncthreads();
    }
    #pragma unroll
    for (int i = 0; i < 4; ++i) {
        const int r = row0 + ty * 4 + i;
        #pragma unroll
        for (int j = 0; j < 4; ++j) {
            const int cidx = col0 + tx * 4 + j;
            if (cidx >= N) continue;
            const size_t idx = (size_t)r * N + cidx;
            float dot = acc[i][j];
            if (cacc) { dot += cacc[idx]; cacc[idx] = dot; }
            const float ch = dot + bias[cidx];
            const float vv = (v[idx] + ch) * 0.5f;
            const float sp = (vv >= 1.0f) ? 1.0f : 0.0f;
            v[idx] = (sp != 0.0f) ? 0.0f : vv;
            s[idx] = sp;
        }
    }
}

// --------------------------------------------------------------------- launch
extern "C" void kernel_launch(void* const* d_in, const int* in_sizes, int n_in,
                              void* d_out, int out_size, void* d_ws, size_t ws_size,
                              hipStream_t stream) {
    const float* x  = (const float*)d_in[0];
    const float* W1 = (const float*)d_in[1];
    const float* b1 = (const float*)d_in[2];
    const float* W2 = (const float*)d_in[3];
    const float* b2 = (const float*)d_in[4];
    const float* W3 = (const float*)d_in[5];
    const float* b3 = (const float*)d_in[6];
    float* out = (float*)d_out;

    const int Bb = 1024, D = 4000, H = 2048, O = 1000, Op = 1024, T = 10;
    const int KP = 4160, CHP = 416, CH = 400;
    const int MS = T * Bb;               // 10240 stacked rows
    const float SC1 = 1.0f / 65536.0f;   // 2^-16 (x and W1 both 2^8-scaled)

    // ---- workspace layout (byte offsets, 4 KiB aligned)
    char* base = (char*)d_ws;
    unsigned*    hdr = (unsigned*)(base);                 //   4,096 (max2, max3)
    float*       b3p = (float*)(base + 4096);             //   4,096
    signed char* w2d = (signed char*)(base + 8192);       // 12,582,912
    signed char* w3d = (signed char*)(base + 12591104);   //  6,291,456
    signed char* s1  = (signed char*)(base + 18882560);   // 20,971,520
    signed char* s2  = (signed char*)(base + 39854080);   // 20,971,520
    float*       P   = (float*)(base + 60825600);         // 83,886,080 (C3 alias)
    _Float16*    xs  = (_Float16*)(base + 144711680);     // 17,039,360
    _Float16*    w1s = (_Float16*)(base + 161751040);     // 34,078,720
    float*       C3  = P;                                 // P dead after scan2
    const size_t need = 195829760;

    if (ws_size < need) {
        const size_t BH = (size_t)Bb * H, BO = (size_t)Bb * O;
        float* ws = (float*)d_ws;
        float* c1 = ws;        float* v1 = c1 + BH;  float* s1f = v1 + BH;
        float* v2 = s1f + BH;  float* s2f = v2 + BH; float* v3 = s2f + BH;
        hipMemsetAsync(d_ws, 0, (5 * BH + BO) * sizeof(float), stream);
        const dim3 blk(256);
        for (int t = 0; t < T; ++t) {
            gemm_lif_f32fb<<<dim3(H / 64, Bb / 64), blk, 0, stream>>>(
                x + t * CH, D, W1 + (size_t)t * CH * H, H, b1, c1, v1, s1f, Bb, H, CH);
            gemm_lif_f32fb<<<dim3(H / 64, Bb / 64), blk, 0, stream>>>(
                s1f, H, W2, H, b2, nullptr, v2, s2f, Bb, H, H);
            gemm_lif_f32fb<<<dim3((O + 63) / 64, Bb / 64), blk, 0, stream>>>(
                s2f, H, W3, O, b3, nullptr, v3, out, Bb, O, H);
        }
        return;
    }

    // ---- prep: header zero, padded bias3, maxabs (fused), splits
    hipMemsetAsync(base, 0, 8192, stream);
    hipMemcpyAsync(b3p, b3, O * sizeof(float), hipMemcpyDeviceToDevice, stream);
    maxabs2_kern<<<dim3(384, 2), 256, 0, stream>>>(W2, H * H, W3, H * O, hdr);
    dsplit_t<<<dim3(H / 32, H / 32), 256, 0, stream>>>(W2, H, H, H, w2d, hdr + 0);
    dsplit_t<<<dim3(H / 32, Op / 32), 256, 0, stream>>>(W3, H, O, Op, w3d, hdr + 1);
    split2_w1<<<dim3(KP / 32, H / 32), 256, 0, stream>>>(W1, w1s);
    splitx<<<dim3((Bb * KP + 255) / 256), 256, 0, stream>>>(x, xs);

    const size_t PSx  = (size_t)Bb * KP;
    const size_t PSw1 = (size_t)H * KP;

    // ---- L1: P_t = x_t @ W1_t (f16 2-plane, stacked M=10240)
    gemm_f16_l1<<<(MS / 128) * (H / 128), 256, 0, stream>>>(
        xs, PSx, KP, w1s, PSw1, KP, CHP, CHP, SC1, P, H, 1);
    // ---- LIF1 (prefix) -> s1 (i8)
    lif_scan<<<(Bb * (H / 4) + 255) / 256, 256, 0, stream>>>(
        P, b1, s1, nullptr, H, H, 1);
    // ---- L2: C2 = s1 @ W2 (i8 digits) -> P
    gemm_i8<<<(MS / 128) * (H / 64), 256, 0, stream>>>(
        s1, H, w2d, (size_t)H * H, H, H, hdr + 0, P, H, 2);
    // ---- LIF2 -> s2 (i8)
    lif_scan<<<(Bb * (H / 4) + 255) / 256, 256, 0, stream>>>(
        P, b2, s2, nullptr, H, H, 0);
    // ---- L3: C3 = s2 @ W3 (i8 digits) -> C3 (aliases P)
    gemm_i8<<<(MS / 128) * (Op / 64), 256, 0, stream>>>(
        s2, H, w3d, (size_t)Op * H, H, H, hdr + 1, C3, Op, 1);
    // ---- LIF3 -> out (t=9, n<1000)
    lif_scan<<<(Bb * (Op / 4) + 255) / 256, 256, 0, stream>>>(
        C3, b3p, nullptr, out, Op, O, 0);
}

// Round 10
// 488.687 us; speedup vs baseline: 1.0504x; 1.0504x over previous
//
#include <hip/hip_runtime.h>
#include <hip/hip_bf16.h>
#include <math.h>

// SNN 3-layer LIF MLP, T=10, fp32 reference.
// R10: revert gemm_i8 to R8's BK=64 (R9's BK=128 raised MfmaUtil only
// 37.5->39.5 and regressed total via L3 side-effects -> barrier drain is NOT
// the binding stall; 44%-of-ceiling is the HIP-source structural plateau).
// Added __launch_bounds__(256,3) to gemm_f16_l1 (32 KB LDS allows 3 blocks/CU;
// cap VGPRs so the allocator doesn't block it).

typedef _Float16 half8 __attribute__((ext_vector_type(8)));
typedef __attribute__((ext_vector_type(4))) float f32x4;
typedef __attribute__((ext_vector_type(4))) int i32x4;

#ifndef __has_builtin
#define __has_builtin(x) 0
#endif
#if __has_builtin(__builtin_amdgcn_global_load_lds)
#define HAS_GLLDS 1
#else
#define HAS_GLLDS 0
#endif

// slot swizzle for (row r in [0,64), chunk c in [0,4)) -> granule slot
__device__ __forceinline__ int swz(int r, int c) {
    const int s2 = r >> 1;
    return s2 * 8 + ((((r & 1) << 2) + c + s2) & 7);
}

// ------------------------------------------------------------- i8 digit GEMM
// C[M][Npad] = (2^16*S@W2d + 2^8*S@W1d + S@W0d) * 2^-s ; S i8 binary.
// Block tile 128m x 64n, wave tile 64x32, K-iter 64. Measured 0 LDS conflicts.
__global__ __launch_bounds__(256, 3)
void gemm_i8(const signed char* __restrict__ A, int lda,
             const signed char* __restrict__ Bd, size_t bStride, int ldb,
             int K, const unsigned* __restrict__ maxbits,
             float* __restrict__ C, int Npad, int ls)
{
    __shared__ __align__(16) char tiles[5 * 4096];  // A:2 sub-tiles, B:3 planes

    const int tid = threadIdx.x;
    const int b   = blockIdx.x;
    const int xcd = b & 7, ii = b >> 3;
    const int ntp = 1 << ls;
    const int n_tile = xcd * ntp + (ii & (ntp - 1));
    const int m_tile = ii >> ls;
    const int m0 = m_tile * 128, n0 = n_tile * 64;

    const int ss = tid >> 3;
    const int gg = ((tid & 7) - ss) & 7;
    const int rdec = 2 * ss + (gg >> 2);   // 0..63
    const int cdec = gg & 3;
    const int wbase = (tid & ~63) * 16;    // wave-uniform LDS dest base

    const signed char* srcA0 = A + (size_t)(m0 + rdec) * lda + cdec * 16;
    const signed char* srcA1 = A + (size_t)(m0 + 64 + rdec) * lda + cdec * 16;
    const signed char* srcB[3];
    #pragma unroll
    for (int q = 0; q < 3; ++q)
        srcB[q] = Bd + q * bStride + (size_t)(n0 + rdec) * ldb + cdec * 16;

    const int lane = tid & 63, w = tid >> 6;
    const int wm = (w >> 1) * 64, wn = (w & 1) * 32;
    const int lm = lane & 15, ck = lane >> 4;

    int aOff[4], bOff[2];
    #pragma unroll
    for (int i = 0; i < 4; ++i) {
        const int r = wm + i * 16 + lm;
        aOff[i] = (r >> 6) * 4096 + swz(r & 63, ck) * 16;
    }
    #pragma unroll
    for (int j = 0; j < 2; ++j) {
        const int r = wn + j * 16 + lm;
        bOff[j] = 8192 + swz(r, ck) * 16;
    }

    i32x4 acc0[4][2] = {}, acc1[4][2] = {}, acc2[4][2] = {};

    const int nIter = K / 64;
    for (int it = 0; it < nIter; ++it) {
        const int kk = it * 64;
#if HAS_GLLDS
        __builtin_amdgcn_global_load_lds(
            (const __attribute__((address_space(1))) void*)(srcA0 + kk),
            (__attribute__((address_space(3))) void*)(tiles + wbase), 16, 0, 0);
        __builtin_amdgcn_global_load_lds(
            (const __attribute__((address_space(1))) void*)(srcA1 + kk),
            (__attribute__((address_space(3))) void*)(tiles + 4096 + wbase), 16, 0, 0);
        #pragma unroll
        for (int q = 0; q < 3; ++q)
            __builtin_amdgcn_global_load_lds(
                (const __attribute__((address_space(1))) void*)(srcB[q] + kk),
                (__attribute__((address_space(3))) void*)(tiles + 8192 + q * 4096 + wbase),
                16, 0, 0);
#else
        *(float4*)(tiles + tid * 16) = *(const float4*)(srcA0 + kk);
        *(float4*)(tiles + 4096 + tid * 16) = *(const float4*)(srcA1 + kk);
        #pragma unroll
        for (int q = 0; q < 3; ++q)
            *(float4*)(tiles + 8192 + q * 4096 + tid * 16) = *(const float4*)(srcB[q] + kk);
#endif
        __syncthreads();

        i32x4 aF[4], bF[3][2];
        #pragma unroll
        for (int i = 0; i < 4; ++i) aF[i] = *(const i32x4*)(tiles + aOff[i]);
        #pragma unroll
        for (int q = 0; q < 3; ++q)
            #pragma unroll
            for (int j = 0; j < 2; ++j)
                bF[q][j] = *(const i32x4*)(tiles + q * 4096 + bOff[j]);

        #pragma unroll
        for (int i = 0; i < 4; ++i)
            #pragma unroll
            for (int j = 0; j < 2; ++j) {
                acc0[i][j] = __builtin_amdgcn_mfma_i32_16x16x64_i8(aF[i], bF[0][j], acc0[i][j], 0, 0, 0);
                acc1[i][j] = __builtin_amdgcn_mfma_i32_16x16x64_i8(aF[i], bF[1][j], acc1[i][j], 0, 0, 0);
                acc2[i][j] = __builtin_amdgcn_mfma_i32_16x16x64_i8(aF[i], bF[2][j], acc2[i][j], 0, 0, 0);
            }
        __syncthreads();
    }

    // epilogue: exact i64 digit combine, one fp32 round * 2^-s
    const int sexp = 21 - ilogbf(__uint_as_float(*maxbits));
    const float sc = ldexpf(1.0f, -sexp);
    const int rq = ck * 4;
    #pragma unroll
    for (int i = 0; i < 4; ++i) {
        #pragma unroll
        for (int j = 0; j < 2; ++j) {
            const int n = n0 + wn + j * 16 + lm;
            #pragma unroll
            for (int r = 0; r < 4; ++r) {
                const int m = m0 + wm + i * 16 + rq + r;
                const long long v = ((long long)acc0[i][j][r] << 16) +
                                    ((long long)acc1[i][j][r] << 8) +
                                    (long long)acc2[i][j][r];
                C[(size_t)m * Npad + n] = (float)v * sc;
            }
        }
    }
}

// --------------------------------------------------------- L1 f16 2-plane GEMM
// 2 A-planes x 2 B-planes, pairs (0,0)(0,1)(1,0). Block 128x128, wave 64x64.
// launch_bounds(256,3): 32 KB LDS permits 3 blocks/CU; cap VGPR to allow it.
__global__ __launch_bounds__(256, 3)
void gemm_f16_l1(const _Float16* __restrict__ A, size_t aStride, int lda,
                 const _Float16* __restrict__ B, size_t bStride, int ldb,
                 int K, int kChunk, float scale,
                 float* __restrict__ C, int Npad, int ls)
{
    __shared__ __align__(16) char tiles[4 * 8192];

    const int tid = threadIdx.x;
    const int b   = blockIdx.x;
    const int xcd = b & 7, ii = b >> 3;
    const int ntp = 1 << ls;
    const int n_tile = xcd * ntp + (ii & (ntp - 1));
    const int m_tile = ii >> ls;
    const int m0 = m_tile * 128, n0 = n_tile * 128;

    const int t     = m0 >> 10;
    const int kbase = t * kChunk;
    const int arow0 = m0 & 1023;

    int srow[2], schk[2];
    #pragma unroll
    for (int h = 0; h < 2; ++h) {
        const int s   = h * 256 + tid;
        const int sub = s >> 8, sp = s & 255;
        const int ss  = sp >> 3, gg = ((sp & 7) - ss) & 7;
        srow[h] = sub * 64 + 2 * ss + (gg >> 2);
        schk[h] = gg & 3;
    }
    const int wbase = (tid & ~63) * 16;

    const _Float16* srcA[2][2];
    const _Float16* srcB[2][2];
    #pragma unroll
    for (int p = 0; p < 2; ++p)
        #pragma unroll
        for (int h = 0; h < 2; ++h) {
            srcA[p][h] = A + p * aStride + (size_t)(arow0 + srow[h]) * lda + kbase + schk[h] * 8;
            srcB[p][h] = B + p * bStride + (size_t)(n0 + srow[h]) * ldb + kbase + schk[h] * 8;
        }

    const int lane = tid & 63, w = tid >> 6;
    const int wm = (w >> 1) * 64, wn = (w & 1) * 64;
    const int lm = lane & 15, ck = lane >> 4;

    int aOff[4], bOff[4];
    #pragma unroll
    for (int i = 0; i < 4; ++i) {
        const int r = wm + i * 16 + lm;
        aOff[i] = (r >> 6) * 4096 + swz(r & 63, ck) * 16;
        const int r2 = wn + i * 16 + lm;
        bOff[i] = (r2 >> 6) * 4096 + swz(r2 & 63, ck) * 16;
    }

    f32x4 acc[4][4] = {};

    const int nIter = K / 32;
    for (int it = 0; it < nIter; ++it) {
        const int kk = it * 32;
        #pragma unroll
        for (int p = 0; p < 2; ++p)
            #pragma unroll
            for (int h = 0; h < 2; ++h) {
#if HAS_GLLDS
                __builtin_amdgcn_global_load_lds(
                    (const __attribute__((address_space(1))) void*)(srcA[p][h] + kk),
                    (__attribute__((address_space(3))) void*)(tiles + p * 8192 + h * 4096 + wbase),
                    16, 0, 0);
                __builtin_amdgcn_global_load_lds(
                    (const __attribute__((address_space(1))) void*)(srcB[p][h] + kk),
                    (__attribute__((address_space(3))) void*)(tiles + (2 + p) * 8192 + h * 4096 + wbase),
                    16, 0, 0);
#else
                *(float4*)(tiles + p * 8192 + (h * 256 + tid) * 16) = *(const float4*)(srcA[p][h] + kk);
                *(float4*)(tiles + (2 + p) * 8192 + (h * 256 + tid) * 16) = *(const float4*)(srcB[p][h] + kk);
#endif
            }
        __syncthreads();

        half8 aF[2][4], bF[2][4];
        #pragma unroll
        for (int p = 0; p < 2; ++p)
            #pragma unroll
            for (int i = 0; i < 4; ++i) {
                aF[p][i] = *(const half8*)(tiles + p * 8192 + aOff[i]);
                bF[p][i] = *(const half8*)(tiles + (2 + p) * 8192 + bOff[i]);
            }

        constexpr int PA[3] = {0,0,1}, PB[3] = {0,1,0};
        #pragma unroll
        for (int pp = 0; pp < 3; ++pp)
            #pragma unroll
            for (int i = 0; i < 4; ++i)
                #pragma unroll
                for (int j = 0; j < 4; ++j)
                    acc[i][j] = __builtin_amdgcn_mfma_f32_16x16x32_f16(
                        aF[PA[pp]][i], bF[PB[pp]][j], acc[i][j], 0, 0, 0);
        __syncthreads();
    }

    const int rq = ck * 4;
    #pragma unroll
    for (int i = 0; i < 4; ++i)
        #pragma unroll
        for (int j = 0; j < 4; ++j) {
            const int n = n0 + wn + j * 16 + lm;
            #pragma unroll
            for (int r = 0; r < 4; ++r) {
                const int m = m0 + wm + i * 16 + rq + r;
                C[(size_t)m * Npad + n] = acc[i][j][r] * scale;
            }
        }
}

// ------------------------------------------------------------------ LIF scan
__global__ __launch_bounds__(256)
void lif_scan(const float* __restrict__ C, const float* __restrict__ bias,
              signed char* __restrict__ sout,      // i8 spikes, nullable
              float* __restrict__ fout,            // nullable: t=9, n<Nreal
              int Hpad, int Nreal, int prefix)
{
    const int W4 = Hpad >> 2;
    const int idx = blockIdx.x * 256 + threadIdx.x;
    if (idx >= (W4 << 10)) return;
    const int bb = idx / W4, n4 = idx - bb * W4;
    const float4 b4 = *(const float4*)(bias + n4 * 4);
    const float bs[4] = {b4.x, b4.y, b4.z, b4.w};
    float v[4] = {0.f,0.f,0.f,0.f}, c[4] = {0.f,0.f,0.f,0.f};
    for (int t = 0; t < 10; ++t) {
        const size_t row = (size_t)((t << 10) + bb);
        const float4 p4 = *(const float4*)(C + row * Hpad + n4 * 4);
        const float pv[4] = {p4.x, p4.y, p4.z, p4.w};
        float sv[4];
        #pragma unroll
        for (int e = 0; e < 4; ++e) {
            c[e] = prefix ? (c[e] + pv[e]) : pv[e];
            const float vv = (v[e] + (c[e] + bs[e])) * 0.5f;
            const float sp = (vv >= 1.0f) ? 1.0f : 0.0f;
            v[e] = (sp != 0.0f) ? 0.0f : vv;
            sv[e] = sp;
        }
        if (sout) {
            unsigned pack = 0;
            #pragma unroll
            for (int e = 0; e < 4; ++e) pack |= (sv[e] != 0.0f ? 1u : 0u) << (8 * e);
            *(unsigned*)(sout + row * Hpad + n4 * 4) = pack;
        }
        if (fout && t == 9) {
            #pragma unroll
            for (int e = 0; e < 4; ++e) {
                const int n = n4 * 4 + e;
                if (n < Nreal) fout[(size_t)bb * Nreal + n] = sv[e];
            }
        }
    }
}

// --------------------------------------------- fused maxabs (W2 and W3 in one)
__global__ __launch_bounds__(256)
void maxabs2_kern(const float* __restrict__ w2, int n2,
                  const float* __restrict__ w3, int n3,
                  unsigned* __restrict__ out)
{
    const float* w = blockIdx.y ? w3 : w2;
    const int n = blockIdx.y ? n3 : n2;
    float m = 0.f;
    for (int i = blockIdx.x * 256 + threadIdx.x; i < n; i += gridDim.x * 256)
        m = fmaxf(m, fabsf(w[i]));
    #pragma unroll
    for (int off = 32; off > 0; off >>= 1)
        m = fmaxf(m, __shfl_down(m, off, 64));
    if ((threadIdx.x & 63) == 0) atomicMax(out + blockIdx.y, __float_as_uint(m));
}

// ----------------------------------------------- W digit split (3 i8 planes)
__global__ __launch_bounds__(256)
void dsplit_t(const float* __restrict__ W, int K, int Nreal, int Npad,
              signed char* __restrict__ out, const unsigned* __restrict__ maxbits)
{
    __shared__ float tl[32][33];
    const int sexp = 21 - ilogbf(__uint_as_float(*maxbits));
    const float fs = ldexpf(1.0f, sexp);
    const int k0 = blockIdx.x * 32, n0 = blockIdx.y * 32;
    const int tx = threadIdx.x & 31, ty = threadIdx.x >> 5;
    #pragma unroll
    for (int i = 0; i < 4; ++i) {
        const int k = k0 + ty + i * 8, n = n0 + tx;
        tl[ty + i * 8][tx] = (n < Nreal) ? W[(size_t)k * Nreal + n] : 0.f;
    }
    __syncthreads();
    const size_t plane = (size_t)Npad * K;
    #pragma unroll
    for (int i = 0; i < 4; ++i) {
        const int n = n0 + ty + i * 8, k = k0 + tx;
        int wi = (int)lrintf(tl[tx][ty + i * 8] * fs);
        const int d0 = ((wi + 128) & 255) - 128; wi = (wi - d0) >> 8;
        const int d1 = ((wi + 128) & 255) - 128; wi = (wi - d1) >> 8;
        const size_t idx = (size_t)n * K + k;
        out[idx]             = (signed char)wi;   // high digit (2^16)
        out[plane + idx]     = (signed char)d1;   // mid  digit (2^8)
        out[2 * plane + idx] = (signed char)d0;   // low  digit (2^0)
    }
}

// ------------------------------------------------- L1 f16 splits (2^8-scaled)
__device__ __forceinline__ void f16split2(float val, _Float16& hi, _Float16& mid) {
    const float vs = val * 256.0f;
    hi = (_Float16)vs;
    mid = (_Float16)(vs - (float)hi);
}

__global__ __launch_bounds__(256)
void split2_w1(const float* __restrict__ W1, _Float16* __restrict__ out)
{
    __shared__ float tl[32][33];
    const int kk0 = blockIdx.x * 32, n0 = blockIdx.y * 32;
    const int tx = threadIdx.x & 31, ty = threadIdx.x >> 5;
    #pragma unroll
    for (int i = 0; i < 4; ++i) {
        const int kk = kk0 + ty + i * 8;
        const int tt = kk / 416, j = kk - tt * 416;
        tl[ty + i * 8][tx] = (j < 400) ? W1[(size_t)(tt * 400 + j) * 2048 + (n0 + tx)] : 0.f;
    }
    __syncthreads();
    const size_t plane = (size_t)2048 * 4160;
    #pragma unroll
    for (int i = 0; i < 4; ++i) {
        const int n = n0 + ty + i * 8, kk = kk0 + tx;
        _Float16 hi, mid;
        f16split2(tl[tx][ty + i * 8], hi, mid);
        const size_t idx = (size_t)n * 4160 + kk;
        out[idx] = hi; out[plane + idx] = mid;
    }
}

__global__ __launch_bounds__(256)
void splitx(const float* __restrict__ x, _Float16* __restrict__ out)
{
    const int id = blockIdx.x * 256 + threadIdx.x;
    if (id >= 1024 * 4160) return;
    const int m = id / 4160, kk = id - m * 4160;
    const int tt = kk / 416, j = kk - tt * 416;
    const float val = (j < 400) ? x[(size_t)m * 4000 + tt * 400 + j] : 0.f;
    const size_t PS = (size_t)1024 * 4160;
    _Float16 hi, mid;
    f16split2(val, hi, mid);
    out[id] = hi; out[PS + id] = mid;
}

// -------------------------------------- fallback fp32 path (small workspace)
__global__ __launch_bounds__(256)
void gemm_lif_f32fb(const float* __restrict__ A, int lda,
                    const float* __restrict__ B, int ldb,
                    const float* __restrict__ bias,
                    float* __restrict__ cacc, float* __restrict__ v,
                    float* __restrict__ s, int M, int N, int K)
{
    __shared__ float As[16][68];
    __shared__ float Bs[16][68];
    const int tid = threadIdx.x;
    const int tx = tid & 15, ty = tid >> 4;
    const int row0 = blockIdx.y * 64, col0 = blockIdx.x * 64;
    const int am = tid >> 2, ak = (tid & 3) * 4;
    const int bk = tid >> 4, bn = (tid & 15) * 4;
    float acc[4][4];
    #pragma unroll
    for (int i = 0; i < 4; ++i)
        #pragma unroll
        for (int j = 0; j < 4; ++j) acc[i][j] = 0.f;
    for (int k0 = 0; k0 < K; k0 += 16) {
        const float4 a4 = *(const float4*)(A + (size_t)(row0 + am) * lda + (k0 + ak));
        As[ak + 0][am] = a4.x; As[ak + 1][am] = a4.y;
        As[ak + 2][am] = a4.z; As[ak + 3][am] = a4.w;
        {
            const int col = col0 + bn;
            const float* bp = B + (size_t)(k0 + bk) * ldb + col;
            float4 b4;
            if (col + 3 < N) b4 = *(const float4*)bp;
            else {
                b4.x = (col + 0 < N) ? bp[0] : 0.f;
                b4.y = (col + 1 < N) ? bp[1] : 0.f;
                b4.z = (col + 2 < N) ? bp[2] : 0.f;
                b4.w = 0.f;
            }
            *(float4*)&Bs[bk][bn] = b4;
        }
        __syncthreads();
        #pragma unroll
        for (int kk = 0; kk < 16; ++kk) {
            float af[4], bf[4];
            #pragma unroll
            for (int i = 0; i < 4; ++i) af[i] = As[kk][ty * 4 + i];
            #pragma unroll
            for (int j = 0; j < 4; ++j) bf[j] = Bs[kk][tx * 4 + j];
            #pragma unroll
            for (int i = 0; i < 4; ++i)
                #pragma unroll
                for (int j = 0; j < 4; ++j) acc[i][j] += af[i] * bf[j];
        }
        __syncthreads();
    }
    #pragma unroll
    for (int i = 0; i < 4; ++i) {
        const int r = row0 + ty * 4 + i;
        #pragma unroll
        for (int j = 0; j < 4; ++j) {
            const int cidx = col0 + tx * 4 + j;
            if (cidx >= N) continue;
            const size_t idx = (size_t)r * N + cidx;
            float dot = acc[i][j];
            if (cacc) { dot += cacc[idx]; cacc[idx] = dot; }
            const float ch = dot + bias[cidx];
            const float vv = (v[idx] + ch) * 0.5f;
            const float sp = (vv >= 1.0f) ? 1.0f : 0.0f;
            v[idx] = (sp != 0.0f) ? 0.0f : vv;
            s[idx] = sp;
        }
    }
}

// --------------------------------------------------------------------- launch
extern "C" void kernel_launch(void* const* d_in, const int* in_sizes, int n_in,
                              void* d_out, int out_size, void* d_ws, size_t ws_size,
                              hipStream_t stream) {
    const float* x  = (const float*)d_in[0];
    const float* W1 = (const float*)d_in[1];
    const float* b1 = (const float*)d_in[2];
    const float* W2 = (const float*)d_in[3];
    const float* b2 = (const float*)d_in[4];
    const float* W3 = (const float*)d_in[5];
    const float* b3 = (const float*)d_in[6];
    float* out = (float*)d_out;

    const int Bb = 1024, D = 4000, H = 2048, O = 1000, Op = 1024, T = 10;
    const int KP = 4160, CHP = 416, CH = 400;
    const int MS = T * Bb;               // 10240 stacked rows
    const float SC1 = 1.0f / 65536.0f;   // 2^-16 (x and W1 both 2^8-scaled)

    // ---- workspace layout (byte offsets, 4 KiB aligned)
    char* base = (char*)d_ws;
    unsigned*    hdr = (unsigned*)(base);                 //   4,096 (max2, max3)
    float*       b3p = (float*)(base + 4096);             //   4,096
    signed char* w2d = (signed char*)(base + 8192);       // 12,582,912
    signed char* w3d = (signed char*)(base + 12591104);   //  6,291,456
    signed char* s1  = (signed char*)(base + 18882560);   // 20,971,520
    signed char* s2  = (signed char*)(base + 39854080);   // 20,971,520
    float*       P   = (float*)(base + 60825600);         // 83,886,080 (C3 alias)
    _Float16*    xs  = (_Float16*)(base + 144711680);     // 17,039,360
    _Float16*    w1s = (_Float16*)(base + 161751040);     // 34,078,720
    float*       C3  = P;                                 // P dead after scan2
    const size_t need = 195829760;

    if (ws_size < need) {
        const size_t BH = (size_t)Bb * H, BO = (size_t)Bb * O;
        float* ws = (float*)d_ws;
        float* c1 = ws;        float* v1 = c1 + BH;  float* s1f = v1 + BH;
        float* v2 = s1f + BH;  float* s2f = v2 + BH; float* v3 = s2f + BH;
        hipMemsetAsync(d_ws, 0, (5 * BH + BO) * sizeof(float), stream);
        const dim3 blk(256);
        for (int t = 0; t < T; ++t) {
            gemm_lif_f32fb<<<dim3(H / 64, Bb / 64), blk, 0, stream>>>(
                x + t * CH, D, W1 + (size_t)t * CH * H, H, b1, c1, v1, s1f, Bb, H, CH);
            gemm_lif_f32fb<<<dim3(H / 64, Bb / 64), blk, 0, stream>>>(
                s1f, H, W2, H, b2, nullptr, v2, s2f, Bb, H, H);
            gemm_lif_f32fb<<<dim3((O + 63) / 64, Bb / 64), blk, 0, stream>>>(
                s2f, H, W3, O, b3, nullptr, v3, out, Bb, O, H);
        }
        return;
    }

    // ---- prep: header zero, padded bias3, maxabs (fused), splits
    hipMemsetAsync(base, 0, 8192, stream);
    hipMemcpyAsync(b3p, b3, O * sizeof(float), hipMemcpyDeviceToDevice, stream);
    maxabs2_kern<<<dim3(384, 2), 256, 0, stream>>>(W2, H * H, W3, H * O, hdr);
    dsplit_t<<<dim3(H / 32, H / 32), 256, 0, stream>>>(W2, H, H, H, w2d, hdr + 0);
    dsplit_t<<<dim3(H / 32, Op / 32), 256, 0, stream>>>(W3, H, O, Op, w3d, hdr + 1);
    split2_w1<<<dim3(KP / 32, H / 32), 256, 0, stream>>>(W1, w1s);
    splitx<<<dim3((Bb * KP + 255) / 256), 256, 0, stream>>>(x, xs);

    const size_t PSx  = (size_t)Bb * KP;
    const size_t PSw1 = (size_t)H * KP;

    // ---- L1: P_t = x_t @ W1_t (f16 2-plane, stacked M=10240)
    gemm_f16_l1<<<(MS / 128) * (H / 128), 256, 0, stream>>>(
        xs, PSx, KP, w1s, PSw1, KP, CHP, CHP, SC1, P, H, 1);
    // ---- LIF1 (prefix) -> s1 (i8)
    lif_scan<<<(Bb * (H / 4) + 255) / 256, 256, 0, stream>>>(
        P, b1, s1, nullptr, H, H, 1);
    // ---- L2: C2 = s1 @ W2 (i8 digits) -> P
    gemm_i8<<<(MS / 128) * (H / 64), 256, 0, stream>>>(
        s1, H, w2d, (size_t)H * H, H, H, hdr + 0, P, H, 2);
    // ---- LIF2 -> s2 (i8)
    lif_scan<<<(Bb * (H / 4) + 255) / 256, 256, 0, stream>>>(
        P, b2, s2, nullptr, H, H, 0);
    // ---- L3: C3 = s2 @ W3 (i8 digits) -> C3 (aliases P)
    gemm_i8<<<(MS / 128) * (Op / 64), 256, 0, stream>>>(
        s2, H, w3d, (size_t)Op * H, H, H, hdr + 1, C3, Op, 1);
    // ---- LIF3 -> out (t=9, n<1000)
    lif_scan<<<(Bb * (Op / 4) + 255) / 256, 256, 0, stream>>>(
        C3, b3p, nullptr, out, Op, O, 0);
}